// Round 1
// baseline (227.785 us; speedup 1.0000x reference)
//
#include <hip/hip_runtime.h>

// bpd_cuda: super-BPD boundary angle diff, 512x512.
// Stage 1: per-pixel parent (angle-bin direction, root if OOB or angle gap > theta_a)
// Stage 2: min-label CC via ECL-CC union-find (hook larger root onto smaller ->
//          converged root == min index per component == FastSV's converged result)
// Stage 3: labels = find(i), c3 = pf[pf[pf[i]]]
// Stage 4: out[i,j,{right,down}] = wrapped |ang[c3[i]] - ang[c3[n]]| where labels differ

static constexpr double PI_D = 3.14159265;

__device__ __constant__ int c_DH[8] = {1, 1, 0, -1, -1, -1, 0, 1};
__device__ __constant__ int c_DW[8] = {0, 1, 1, 1, 0, -1, -1, -1};

// static fallback scratch (4 int arrays for N<=512*512) in case ws_size is small
__device__ int g_fb[4 * 262144];

__device__ __forceinline__ int uf_rep(int idx, int* par) {
    int curr = par[idx];
    if (curr != idx) {
        int prev = idx, next;
        while (curr > (next = par[curr])) {
            par[prev] = next;   // benign monotone-decreasing compression race
            prev = curr;
            curr = next;
        }
    }
    return curr;
}

__device__ __forceinline__ void uf_union(int u, int v, int* par) {
    int ru = uf_rep(u, par);
    int rv = uf_rep(v, par);
    bool repeat;
    do {
        repeat = false;
        if (ru != rv) {
            int ret;
            if (rv < ru) {
                if ((ret = atomicCAS(&par[ru], ru, rv)) != ru) { ru = ret; repeat = true; }
            } else {
                if ((ret = atomicCAS(&par[rv], rv, ru)) != rv) { rv = ret; repeat = true; }
            }
        }
    } while (repeat);
}

__global__ void k_parents(const float* __restrict__ ang,
                          const int* __restrict__ hp, const int* __restrict__ wp,
                          const int* __restrict__ tap,
                          int N, int* __restrict__ pf, int* __restrict__ par) {
    int t = blockIdx.x * blockDim.x + threadIdx.x;
    if (t >= N) return;
    const int H = hp[0], W = wp[0];
    const int i = t / W, j = t - i * W;
    const float a = ang[t];
    const float a8 = (float)(PI_D / 8.0);
    const float a4 = (float)(PI_D / 4.0);
    // jnp.round == round-half-to-even == rintf (default rounding mode)
    float posf = rintf((a + a8) / a4);
    if (posf >= 8.0f) posf -= 8.0f;
    const int pos = (int)posf;
    const int nh = i + c_DH[pos];
    const int nw = j + c_DW[pos];
    const bool inb = (nh >= 0) & (nh < H) & (nw >= 0) & (nw < W);
    const int nhc = min(max(nh, 0), H - 1);
    const int nwc = min(max(nw, 0), W - 1);
    const float an = ang[nhc * W + nwc];
    float ad = fabsf(a - an);
    const float twopi = (float)(2.0 * PI_D);
    ad = fminf(ad, twopi - ad);
    const float thr = (float)((double)tap[0] * PI_D / 180.0);
    const bool is_root = (!inb) || (ad > thr);
    pf[t] = is_root ? t : (nhc * W + nwc);   // pf[t]==t  <=>  root
    par[t] = t;
}

__global__ void k_union(const int* __restrict__ pf,
                        const int* __restrict__ hp, const int* __restrict__ wp,
                        int N, int* par) {
    int t = blockIdx.x * blockDim.x + threadIdx.x;
    if (t >= N) return;
    const int p = pf[t];
    if (p != t) {             // non-root: only the pixel<->parent edge
        uf_union(t, p, par);
        return;
    }
    // root pixel: merge_nearby_root_pixels window, dh in [0,2], dw in [-3,2],
    // both endpoints roots, neighbor within [0,H-2]x[0,W-2]
    const int H = hp[0], W = wp[0];
    const int i = t / W, j = t - i * W;
    for (int dh = 0; dh <= 2; ++dh) {
        const int nh = i + dh;
        if (nh > H - 2) break;
        const int base = nh * W;
        for (int dw = -3; dw <= 2; ++dw) {
            if (dh == 0 && dw == 0) continue;
            const int nw = j + dw;
            if ((unsigned)nw > (unsigned)(W - 2)) continue;
            const int nt = base + nw;
            if (pf[nt] == nt) uf_union(t, nt, par);
        }
    }
}

__global__ void k_flatten(const int* __restrict__ pf, int N,
                          int* par, int* __restrict__ labels, int* __restrict__ c3) {
    int t = blockIdx.x * blockDim.x + threadIdx.x;
    if (t >= N) return;
    labels[t] = uf_rep(t, par);    // converged root = min index in component
    int p = pf[t];
    p = pf[p];
    p = pf[p];
    c3[t] = p;
}

__global__ void k_output(const float* __restrict__ ang,
                         const int* __restrict__ labels, const int* __restrict__ c3,
                         const int* __restrict__ hp, const int* __restrict__ wp,
                         int N, float* __restrict__ out) {
    int t = blockIdx.x * blockDim.x + threadIdx.x;
    if (t >= N) return;
    const int H = hp[0], W = wp[0];
    const int i = t / W, j = t - i * W;
    const float twopi = (float)(2.0 * PI_D);
    const int l = labels[t];
    const float ac = ang[c3[t]];
    float r0 = 0.0f, r1 = 0.0f;
    if (j + 1 < W) {                      // right neighbor
        const int nidx = t + 1;
        if (labels[nidx] != l) {
            float ad = fabsf(ac - ang[c3[nidx]]);
            r0 = fminf(ad, twopi - ad);
        }
    }
    if (i + 1 < H) {                      // down neighbor
        const int nidx = t + W;
        if (labels[nidx] != l) {
            float ad = fabsf(ac - ang[c3[nidx]]);
            r1 = fminf(ad, twopi - ad);
        }
    }
    reinterpret_cast<float2*>(out)[t] = make_float2(r0, r1);
}

extern "C" void kernel_launch(void* const* d_in, const int* in_sizes, int n_in,
                              void* d_out, int out_size, void* d_ws, size_t ws_size,
                              hipStream_t stream) {
    const float* ang = (const float*)d_in[0];
    const int* hp  = (const int*)d_in[1];
    const int* wp  = (const int*)d_in[2];
    const int* tap = (const int*)d_in[3];
    const int N = in_sizes[0];

    int* base = (int*)d_ws;
    if (ws_size < (size_t)4 * (size_t)N * sizeof(int) && N <= 262144) {
        void* p = nullptr;
        hipGetSymbolAddress(&p, HIP_SYMBOL(g_fb));   // host-side query; capture-safe
        base = (int*)p;
    }
    int* pf     = base;
    int* par    = base + N;
    int* labels = base + 2 * N;
    int* c3     = base + 3 * N;

    const int threads = 256;
    const int blocks = (N + threads - 1) / threads;
    k_parents<<<blocks, threads, 0, stream>>>(ang, hp, wp, tap, N, pf, par);
    k_union  <<<blocks, threads, 0, stream>>>(pf, hp, wp, N, par);
    k_flatten<<<blocks, threads, 0, stream>>>(pf, N, par, labels, c3);
    k_output <<<blocks, threads, 0, stream>>>(ang, labels, c3, hp, wp, N, (float*)d_out);
}

// Round 2
// 209.612 us; speedup vs baseline: 1.0867x; 1.0867x over previous
//
#include <hip/hip_runtime.h>

// bpd_cuda: super-BPD boundary angle diff, 512x512.
// R2: hierarchical min-label CC.
//   k_parents : per-pixel parent pointer (angle bin dir; root if OOB or gap > theta_a)
//   k_local   : per 32x32 tile, union-find in LDS over intra-tile edges
//   k_global  : global union-find (atomicMin min-hooking) over cross-tile edges only
//   k_flatten : labels = find(t); c3 = pf^3
//   k_output  : wrapped |ang[c3[i]] - ang[c3[n]]| for right/down where labels differ
// All par mutations are atomicMin -> monotone decreasing, race-free by construction.
// Final root per component == min flat index == FastSV converged label.

static constexpr double PI_D = 3.14159265;
#define TS 32   // tile size (TS x TS per block in k_local)

__device__ __constant__ int c_DH[8] = {1, 1, 0, -1, -1, -1, 0, 1};
__device__ __constant__ int c_DW[8] = {0, 1, 1, 1, 0, -1, -1, -1};

// static fallback scratch (4 int arrays for N<=512*512) in case ws_size is small
__device__ int g_fb[4 * 262144];

// find with path-halving; all writes via atomicMin (monotone, benign races)
__device__ __forceinline__ int uf_find(int x, int* par) {
    while (true) {
        int p = par[x];
        if (p == x) return x;
        int gp = par[p];
        if (gp == p) return p;
        atomicMin(&par[x], gp);
        x = gp;
    }
}

// lock-free min-hooking union: always hook larger root under smaller
__device__ __forceinline__ void uf_unite(int u, int v, int* par) {
    int ru = uf_find(u, par);
    int rv = uf_find(v, par);
    while (ru != rv) {
        if (ru > rv) { int t = ru; ru = rv; rv = t; }   // ru < rv
        int old = atomicMin(&par[rv], ru);
        if (old == rv) return;        // rv was a root: linked, done
        rv = uf_find(old, par);       // rv had been hooked meanwhile; keep merging
        ru = uf_find(ru, par);
    }
}

__global__ void k_parents(const float* __restrict__ ang,
                          const int* __restrict__ hp, const int* __restrict__ wp,
                          const int* __restrict__ tap,
                          int N, int* __restrict__ pf, int* __restrict__ par) {
    int t = blockIdx.x * blockDim.x + threadIdx.x;
    if (t >= N) return;
    const int H = hp[0], W = wp[0];
    const int i = t / W, j = t - i * W;
    const float a = ang[t];
    const float a8 = (float)(PI_D / 8.0);
    const float a4 = (float)(PI_D / 4.0);
    // jnp.round == round-half-to-even == rintf (default rounding mode)
    float posf = rintf((a + a8) / a4);
    if (posf >= 8.0f) posf -= 8.0f;
    const int pos = (int)posf;
    const int nh = i + c_DH[pos];
    const int nw = j + c_DW[pos];
    const bool inb = (nh >= 0) & (nh < H) & (nw >= 0) & (nw < W);
    const int nhc = min(max(nh, 0), H - 1);
    const int nwc = min(max(nw, 0), W - 1);
    const float an = ang[nhc * W + nwc];
    float ad = fabsf(a - an);
    const float twopi = (float)(2.0 * PI_D);
    ad = fminf(ad, twopi - ad);
    const float thr = (float)((double)tap[0] * PI_D / 180.0);
    const bool is_root = (!inb) || (ad > thr);
    pf[t] = is_root ? t : (nhc * W + nwc);   // pf[t]==t  <=>  root
    par[t] = t;
}

// per-tile union-find in LDS over edges with both endpoints inside the tile
__global__ void k_local(const int* __restrict__ pf,
                        const int* __restrict__ hp, const int* __restrict__ wp,
                        int N, int* __restrict__ par) {
    const int H = hp[0], W = wp[0];
    const int tx = (W + TS - 1) / TS;
    const int ty = (H + TS - 1) / TS;
    const int ntiles = tx * ty;
    __shared__ int lpar[TS * TS];
    for (int tile = blockIdx.x; tile < ntiles; tile += gridDim.x) {
        const int ti0 = (tile / tx) * TS;
        const int tj0 = (tile % tx) * TS;
        for (int lp = threadIdx.x; lp < TS * TS; lp += blockDim.x) lpar[lp] = lp;
        __syncthreads();
        for (int lp = threadIdx.x; lp < TS * TS; lp += blockDim.x) {
            const int li = lp / TS, lj = lp % TS;
            const int gi = ti0 + li, gj = tj0 + lj;
            if (gi >= H || gj >= W) continue;
            const int g = gi * W + gj;
            const int p = pf[g];
            if (p != g) {
                const int pi = p / W, pj = p - pi * W;
                if (pi >= ti0 && pi < ti0 + TS && pj >= tj0 && pj < tj0 + TS)
                    uf_unite(lp, (pi - ti0) * TS + (pj - tj0), lpar);
            } else {
                // root: window edges (dh in [0,2], dw in [-3,2]), both endpoints roots,
                // neighbor within [0,H-2] x [0,W-2]; here only in-tile neighbors
                for (int dh = 0; dh <= 2; ++dh) {
                    const int nh = gi + dh;
                    if (nh > H - 2) break;
                    if (nh >= ti0 + TS) break;
                    for (int dw = -3; dw <= 2; ++dw) {
                        if (dh == 0 && dw == 0) continue;
                        const int nw = gj + dw;
                        if (nw < 0 || nw > W - 2) continue;
                        if (nw < tj0 || nw >= tj0 + TS) continue;
                        const int n = nh * W + nw;
                        if (pf[n] == n)
                            uf_unite(lp, (nh - ti0) * TS + (nw - tj0), lpar);
                    }
                }
            }
        }
        __syncthreads();
        // publish: global parent = tile-local root's global index (depth-1 forest per tile)
        for (int lp = threadIdx.x; lp < TS * TS; lp += blockDim.x) {
            const int li = lp / TS, lj = lp % TS;
            const int gi = ti0 + li, gj = tj0 + lj;
            if (gi >= H || gj >= W) continue;
            const int lr = uf_find(lp, lpar);
            par[gi * W + gj] = (ti0 + lr / TS) * W + (tj0 + lr % TS);
        }
        __syncthreads();   // before re-init for next tile
    }
}

// global union-find over cross-tile edges only
__global__ void k_global(const int* __restrict__ pf,
                         const int* __restrict__ hp, const int* __restrict__ wp,
                         int N, int* par) {
    int t = blockIdx.x * blockDim.x + threadIdx.x;
    if (t >= N) return;
    const int H = hp[0], W = wp[0];
    const int i = t / W, j = t - i * W;
    const int ti = i / TS, tj = j / TS;
    const int p = pf[t];
    if (p != t) {
        const int pi = p / W, pj = p - pi * W;
        if (pi / TS != ti || pj / TS != tj) uf_unite(t, p, par);
        return;
    }
    for (int dh = 0; dh <= 2; ++dh) {
        const int nh = i + dh;
        if (nh > H - 2) break;
        for (int dw = -3; dw <= 2; ++dw) {
            if (dh == 0 && dw == 0) continue;
            const int nw = j + dw;
            if (nw < 0 || nw > W - 2) continue;
            if (nh / TS == ti && nw / TS == tj) continue;   // handled in k_local
            const int n = nh * W + nw;
            if (pf[n] == n) uf_unite(t, n, par);
        }
    }
}

__global__ void k_flatten(const int* __restrict__ pf, int N,
                          int* par, int* __restrict__ labels, int* __restrict__ c3) {
    int t = blockIdx.x * blockDim.x + threadIdx.x;
    if (t >= N) return;
    labels[t] = uf_find(t, par);   // converged root = min index in component
    int p = pf[t];
    p = pf[p];
    p = pf[p];
    c3[t] = p;
}

__global__ void k_output(const float* __restrict__ ang,
                         const int* __restrict__ labels, const int* __restrict__ c3,
                         const int* __restrict__ hp, const int* __restrict__ wp,
                         int N, float* __restrict__ out) {
    int t = blockIdx.x * blockDim.x + threadIdx.x;
    if (t >= N) return;
    const int H = hp[0], W = wp[0];
    const int i = t / W, j = t - i * W;
    const float twopi = (float)(2.0 * PI_D);
    const int l = labels[t];
    const float ac = ang[c3[t]];
    float r0 = 0.0f, r1 = 0.0f;
    if (j + 1 < W) {                      // right neighbor
        const int nidx = t + 1;
        if (labels[nidx] != l) {
            float ad = fabsf(ac - ang[c3[nidx]]);
            r0 = fminf(ad, twopi - ad);
        }
    }
    if (i + 1 < H) {                      // down neighbor
        const int nidx = t + W;
        if (labels[nidx] != l) {
            float ad = fabsf(ac - ang[c3[nidx]]);
            r1 = fminf(ad, twopi - ad);
        }
    }
    reinterpret_cast<float2*>(out)[t] = make_float2(r0, r1);
}

extern "C" void kernel_launch(void* const* d_in, const int* in_sizes, int n_in,
                              void* d_out, int out_size, void* d_ws, size_t ws_size,
                              hipStream_t stream) {
    const float* ang = (const float*)d_in[0];
    const int* hp  = (const int*)d_in[1];
    const int* wp  = (const int*)d_in[2];
    const int* tap = (const int*)d_in[3];
    const int N = in_sizes[0];

    int* base = (int*)d_ws;
    if (ws_size < (size_t)4 * (size_t)N * sizeof(int) && N <= 262144) {
        void* p = nullptr;
        hipGetSymbolAddress(&p, HIP_SYMBOL(g_fb));   // host-side query; capture-safe
        base = (int*)p;
    }
    int* pf     = base;
    int* par    = base + N;
    int* labels = base + 2 * N;
    int* c3     = base + 3 * N;

    const int threads = 256;
    const int blocks = (N + threads - 1) / threads;
    k_parents<<<blocks, threads, 0, stream>>>(ang, hp, wp, tap, N, pf, par);
    k_local  <<<256,    threads, 0, stream>>>(pf, hp, wp, N, par);
    k_global <<<blocks, threads, 0, stream>>>(pf, hp, wp, N, par);
    k_flatten<<<blocks, threads, 0, stream>>>(pf, N, par, labels, c3);
    k_output <<<blocks, threads, 0, stream>>>(ang, labels, c3, hp, wp, N, (float*)d_out);
}